// Round 1
// baseline (4625.615 us; speedup 1.0000x reference)
//
#include <hip/hip_runtime.h>
#include <hip/hip_bf16.h>

#define BB 64
#define JJ 32
#define NN 4096
#define QD 130
#define KD 128
#define VD 130
#define HH 4
#define CHUNKS 4
#define NCHUNK (NN / CHUNKS)          // 1024
#define TN 32                         // keys per tile
#define PSTRIDE (JJ + JJ + JJ * VD)   // 32 m + 32 l + 32*130 acc = 4224

// ---------------------------------------------------------------- encoder ---
// h = relu(jq @ W1 + b1) [130->64]; q = h @ W2 + b2 [64->512]
__global__ __launch_bounds__(64) void enc_kernel(
        const float* __restrict__ jq,
        const float* __restrict__ W1, const float* __restrict__ b1,
        const float* __restrict__ W2, const float* __restrict__ b2,
        float* __restrict__ qenc) {
    int row = blockIdx.x;          // b*J + j
    int t = threadIdx.x;           // 0..63
    __shared__ float x[QD];
    __shared__ float h[64];
    for (int i = t; i < QD; i += 64) x[i] = jq[row * QD + i];
    __syncthreads();
    float acc = b1[t];
    for (int i = 0; i < QD; ++i) acc += x[i] * W1[i * 64 + t];
    h[t] = fmaxf(acc, 0.f);
    __syncthreads();
    for (int s = 0; s < 8; ++s) {
        int o = t + 64 * s;
        float a = b2[o];
        for (int i = 0; i < 64; ++i) a += h[i] * W2[i * 512 + o];
        qenc[row * 512 + o] = a;
    }
}

// -------------------------------------------------------------- attention ---
// One block per (b, h, chunk): 32 query rows, online softmax over 1024 keys.
// 256 threads = 32 j-groups x 8 lanes. Each lane: 4 keys (scores) and a
// 16-float v-slice (PV), v = 32*c + 4*lane + cc (conflict-free ds_read_b128).
__global__ __launch_bounds__(256) void attn_kernel(
        const float* __restrict__ Kg, const float* __restrict__ Vg,
        const int* __restrict__ maskg, const float* __restrict__ qenc,
        float* __restrict__ part) {
    int blk = blockIdx.x;
    int c = blk & (CHUNKS - 1);
    int bh = blk >> 2;             // CHUNKS==4
    int h = bh & (HH - 1);
    int b = bh >> 2;               // HH==4
    int tid = threadIdx.x;
    int jg = tid >> 3;             // 0..31
    int l8 = tid & 7;

    __shared__ float q_s[JJ][132];
    __shared__ float K_s[TN][132];
    __shared__ float V_s[TN][132];
    __shared__ float p_s[JJ][33];
    __shared__ int   m_s[TN];

    // load q rows for this (b,h)
    const float* qbase = qenc + (size_t)(b * JJ) * 512 + h * KD;
    for (int idx = tid; idx < JJ * KD / 4; idx += 256) {
        int j = idx >> 5;
        int c4 = idx & 31;
        float4 v = *(const float4*)(qbase + j * 512 + c4 * 4);
        *(float4*)(&q_s[j][c4 * 4]) = v;
    }

    float m_run = -1e30f;
    float l_part = 0.f;
    float4 a0 = {0, 0, 0, 0}, a1 = {0, 0, 0, 0}, a2 = {0, 0, 0, 0}, a3 = {0, 0, 0, 0};
    float acct = 0.f;              // tail (v=128+l8) for l8<2

    int n0 = c * NCHUNK;
    const float* Kb = Kg + (size_t)b * NN * KD;
    const float* Vb = Vg + (size_t)b * NN * VD;
    const int* Mb = maskg + b * NN;
    __syncthreads();

    for (int nt = 0; nt < NCHUNK; nt += TN) {
        int nbase = n0 + nt;
        for (int idx = tid; idx < TN * KD / 4; idx += 256) {
            int r = idx >> 5;
            int c4 = idx & 31;
            *(float4*)(&K_s[r][c4 * 4]) = *(const float4*)(Kb + (size_t)(nbase + r) * KD + c4 * 4);
        }
        for (int idx = tid; idx < TN * VD; idx += 256) {
            int r = idx / VD;
            int col = idx - r * VD;
            V_s[r][col] = Vb[(size_t)(nbase + r) * VD + col];
        }
        if (tid < TN) m_s[tid] = Mb[nbase + tid];
        __syncthreads();

        // ---- scores: 4 keys per lane, k-blocked for q reuse
        float d[4][4];
        #pragma unroll
        for (int t4 = 0; t4 < 4; ++t4)
            d[t4][0] = d[t4][1] = d[t4][2] = d[t4][3] = 0.f;
        for (int k = 0; k < KD; k += 4) {
            float4 qv = *(const float4*)(&q_s[jg][k]);
            #pragma unroll
            for (int t4 = 0; t4 < 4; ++t4) {
                float4 kv = *(const float4*)(&K_s[l8 + 8 * t4][k]);
                d[t4][0] += qv.x * kv.x; d[t4][1] += qv.y * kv.y;
                d[t4][2] += qv.z * kv.z; d[t4][3] += qv.w * kv.w;
            }
        }
        float sv[4];
        #pragma unroll
        for (int t4 = 0; t4 < 4; ++t4) {
            float dd = (d[t4][0] + d[t4][1]) + (d[t4][2] + d[t4][3]);
            sv[t4] = m_s[l8 + 8 * t4] ? -1e30f : dd * 0.08838834764831845f;
        }
        float tmax = fmaxf(fmaxf(sv[0], sv[1]), fmaxf(sv[2], sv[3]));
        tmax = fmaxf(tmax, __shfl_xor(tmax, 1));
        tmax = fmaxf(tmax, __shfl_xor(tmax, 2));
        tmax = fmaxf(tmax, __shfl_xor(tmax, 4));
        float m_new = fmaxf(m_run, tmax);
        if (m_new > m_run) {
            float r = expf(m_run - m_new);
            l_part *= r;
            a0.x *= r; a0.y *= r; a0.z *= r; a0.w *= r;
            a1.x *= r; a1.y *= r; a1.z *= r; a1.w *= r;
            a2.x *= r; a2.y *= r; a2.z *= r; a2.w *= r;
            a3.x *= r; a3.y *= r; a3.z *= r; a3.w *= r;
            acct *= r;
            m_run = m_new;
        }
        float psum = 0.f;
        #pragma unroll
        for (int t4 = 0; t4 < 4; ++t4) {
            float p = (sv[t4] > -1e29f) ? expf(sv[t4] - m_run) : 0.f;
            p_s[jg][l8 + 8 * t4] = p;
            psum += p;
        }
        l_part += psum;
        __syncthreads();

        // ---- PV
        for (int n = 0; n < TN; ++n) {
            float p = p_s[jg][n];
            const float* vr = &V_s[n][0];
            float4 v0 = *(const float4*)(vr + 0 * 32 + l8 * 4);
            float4 v1 = *(const float4*)(vr + 1 * 32 + l8 * 4);
            float4 v2 = *(const float4*)(vr + 2 * 32 + l8 * 4);
            float4 v3 = *(const float4*)(vr + 3 * 32 + l8 * 4);
            a0.x += p * v0.x; a0.y += p * v0.y; a0.z += p * v0.z; a0.w += p * v0.w;
            a1.x += p * v1.x; a1.y += p * v1.y; a1.z += p * v1.z; a1.w += p * v1.w;
            a2.x += p * v2.x; a2.y += p * v2.y; a2.z += p * v2.z; a2.w += p * v2.w;
            a3.x += p * v3.x; a3.y += p * v3.y; a3.z += p * v3.z; a3.w += p * v3.w;
            if (l8 < 2) acct += p * vr[128 + l8];
        }
        __syncthreads();
    }

    // reduce l over the 8 lanes of the group
    float lsum = l_part;
    lsum += __shfl_xor(lsum, 1);
    lsum += __shfl_xor(lsum, 2);
    lsum += __shfl_xor(lsum, 4);

    float* P = part + (size_t)blk * PSTRIDE;
    if (l8 == 0) {
        P[jg] = m_run;
        P[JJ + jg] = lsum;
    }
    float* A = P + 2 * JJ + jg * VD;
    A[0 * 32 + l8 * 4 + 0] = a0.x; A[0 * 32 + l8 * 4 + 1] = a0.y;
    A[0 * 32 + l8 * 4 + 2] = a0.z; A[0 * 32 + l8 * 4 + 3] = a0.w;
    A[1 * 32 + l8 * 4 + 0] = a1.x; A[1 * 32 + l8 * 4 + 1] = a1.y;
    A[1 * 32 + l8 * 4 + 2] = a1.z; A[1 * 32 + l8 * 4 + 3] = a1.w;
    A[2 * 32 + l8 * 4 + 0] = a2.x; A[2 * 32 + l8 * 4 + 1] = a2.y;
    A[2 * 32 + l8 * 4 + 2] = a2.z; A[2 * 32 + l8 * 4 + 3] = a2.w;
    A[3 * 32 + l8 * 4 + 0] = a3.x; A[3 * 32 + l8 * 4 + 1] = a3.y;
    A[3 * 32 + l8 * 4 + 2] = a3.z; A[3 * 32 + l8 * 4 + 3] = a3.w;
    if (l8 < 2) A[128 + l8] = acct;
}

// ---------------------------------------------------------------- combine ---
__global__ __launch_bounds__(256) void comb_kernel(
        const float* __restrict__ part, float* __restrict__ attn_out) {
    int bh = blockIdx.x;           // b*H + h
    int h = bh & (HH - 1);
    int b = bh >> 2;
    int tid = threadIdx.x;
    int jg = tid >> 3;
    int l8 = tid & 7;
    __shared__ float w_s[CHUNKS][JJ];
    if (tid < JJ) {
        int j = tid;
        float m[CHUNKS], l[CHUNKS];
        float mmax = -1e30f;
        for (int cc = 0; cc < CHUNKS; ++cc) {
            const float* P = part + (size_t)(bh * CHUNKS + cc) * PSTRIDE;
            m[cc] = P[j];
            l[cc] = P[JJ + j];
            mmax = fmaxf(mmax, m[cc]);
        }
        float L = 0.f;
        float e[CHUNKS];
        for (int cc = 0; cc < CHUNKS; ++cc) {
            e[cc] = expf(m[cc] - mmax);
            L += l[cc] * e[cc];
        }
        float inv = (L > 0.f) ? 1.0f / L : 0.f;
        for (int cc = 0; cc < CHUNKS; ++cc) w_s[cc][j] = e[cc] * inv;
    }
    __syncthreads();
    for (int v = l8; v < VD; v += 8) {
        float o = 0.f;
        for (int cc = 0; cc < CHUNKS; ++cc) {
            const float* P = part + (size_t)(bh * CHUNKS + cc) * PSTRIDE;
            o += w_s[cc][jg] * P[2 * JJ + jg * VD + v];
        }
        attn_out[(size_t)(b * JJ + jg) * (HH * VD) + h * VD + v] = o;
    }
}

// -------------------------------------------------------------- output MLP --
__global__ __launch_bounds__(64) void mlp_kernel(
        const float* __restrict__ x_in,
        const float* __restrict__ W3, const float* __restrict__ b3,
        const float* __restrict__ W4, const float* __restrict__ b4,
        const float* __restrict__ W5, const float* __restrict__ b5,
        float* __restrict__ out) {
    int row = blockIdx.x;          // b*J + j
    int t = threadIdx.x;
    __shared__ float x[HH * VD];
    __shared__ float h1[64];
    __shared__ float h2[32];
    for (int i = t; i < HH * VD; i += 64) x[i] = x_in[(size_t)row * (HH * VD) + i];
    __syncthreads();
    float a = b3[t];
    for (int i = 0; i < HH * VD; ++i) a += x[i] * W3[i * 64 + t];
    h1[t] = fmaxf(a, 0.f);
    __syncthreads();
    if (t < 32) {
        float a2 = b4[t];
        for (int i = 0; i < 64; ++i) a2 += h1[i] * W4[i * 32 + t];
        h2[t] = fmaxf(a2, 0.f);
    }
    __syncthreads();
    if (t == 0) {
        float a3 = b5[0];
        for (int i = 0; i < 32; ++i) a3 += h2[i] * W5[i];
        out[row] = a3;
    }
}

extern "C" void kernel_launch(void* const* d_in, const int* in_sizes, int n_in,
                              void* d_out, int out_size, void* d_ws, size_t ws_size,
                              hipStream_t stream) {
    const float* jq = (const float*)d_in[0];
    const float* Kg = (const float*)d_in[1];
    const float* Vg = (const float*)d_in[2];
    const int* mask = (const int*)d_in[3];
    const float* W1 = (const float*)d_in[4];
    const float* b1 = (const float*)d_in[5];
    const float* W2 = (const float*)d_in[6];
    const float* b2 = (const float*)d_in[7];
    const float* W3 = (const float*)d_in[8];
    const float* b3 = (const float*)d_in[9];
    const float* W4 = (const float*)d_in[10];
    const float* b4 = (const float*)d_in[11];
    const float* W5 = (const float*)d_in[12];
    const float* b5 = (const float*)d_in[13];
    float* out = (float*)d_out;

    float* ws = (float*)d_ws;
    float* qenc = ws;                                   // B*J*512      = 1,048,576 f
    float* part = qenc + (size_t)BB * JJ * HH * KD;     // B*H*C*PSTRIDE= 4,325,376 f
    float* attn = part + (size_t)BB * HH * CHUNKS * PSTRIDE; // B*J*520 = 1,064,960 f

    enc_kernel<<<BB * JJ, 64, 0, stream>>>(jq, W1, b1, W2, b2, qenc);
    attn_kernel<<<BB * HH * CHUNKS, 256, 0, stream>>>(Kg, Vg, mask, qenc, part);
    comb_kernel<<<BB * HH, 256, 0, stream>>>(part, attn);
    mlp_kernel<<<BB * JJ, 64, 0, stream>>>(attn, W3, b3, W4, b4, W5, b5, out);
}

// Round 2
// 695.993 us; speedup vs baseline: 6.6461x; 6.6461x over previous
//
#include <hip/hip_runtime.h>
#include <hip/hip_bf16.h>

#define BB 64
#define JJ 32
#define NN 4096
#define QD 130
#define KD 128
#define VD 130
#define HH 4
#define CHUNKS 4
#define NCHUNK (NN / CHUNKS)          // 1024
#define TK 64                         // keys per score tile
#define PSTRIDE (JJ + JJ + JJ * VD)   // 4224 floats per partial block

// ---------------------------------------------------------------- encoder ---
__global__ __launch_bounds__(64) void enc_kernel(
        const float* __restrict__ jq,
        const float* __restrict__ W1, const float* __restrict__ b1,
        const float* __restrict__ W2, const float* __restrict__ b2,
        float* __restrict__ qenc) {
    int row = blockIdx.x;          // b*J + j
    int t = threadIdx.x;           // 0..63
    __shared__ float x[QD];
    __shared__ float h[64];
    for (int i = t; i < QD; i += 64) x[i] = jq[row * QD + i];
    __syncthreads();
    float acc = b1[t];
    for (int i = 0; i < QD; ++i) acc += x[i] * W1[i * 64 + t];
    h[t] = fmaxf(acc, 0.f);
    __syncthreads();
    for (int s = 0; s < 8; ++s) {
        int o = t + 64 * s;
        float a = b2[o];
        for (int i = 0; i < 64; ++i) a += h[i] * W2[i * 512 + o];
        qenc[row * 512 + o] = a;
    }
}

// -------------------------------------------------------------- attention ---
// One block per (b, h, chunk): 32 queries x 1024 keys, online softmax.
// Score phase: 256 thr = 16 qg (2 queries) x 16 kl (4 keys at kl+16t).
// PV phase:    256 thr = 8 qg4 (4 queries) x 32 vl (float4 of V, +tail).
__global__ __launch_bounds__(256) void attn_kernel(
        const float* __restrict__ Kg, const float* __restrict__ Vg,
        const int* __restrict__ maskg, const float* __restrict__ qenc,
        float* __restrict__ part) {
    int blk = blockIdx.x;
    int c = blk & (CHUNKS - 1);
    int bh = blk >> 2;
    int h = bh & (HH - 1);
    int b = bh >> 2;
    int tid = threadIdx.x;

    int qg = tid >> 4;             // 0..15, queries 2qg,2qg+1
    int kl = tid & 15;             // 0..15, keys kl+16t
    int qg4 = tid >> 5;            // 0..7, queries 4qg4..+3
    int vl = tid & 31;             // 0..31, v-cols 4vl..+3

    __shared__ float q_s[JJ][132];
    __shared__ float K_s[TK][132];
    __shared__ float V_s[32][132];
    __shared__ float p_s[TK][36];
    __shared__ float r_s[JJ];
    __shared__ float mrun_s[JJ];
    __shared__ float lrun_s[JJ];
    __shared__ int   msk_s[TK];

    const float* qbase = qenc + (size_t)(b * JJ) * 512 + h * KD;
    for (int idx = tid; idx < JJ * KD / 4; idx += 256) {
        int j = idx >> 5, c4 = idx & 31;
        *(float4*)&q_s[j][c4 * 4] = *(const float4*)(qbase + j * 512 + c4 * 4);
    }
    if (tid < JJ) { mrun_s[tid] = -1e30f; lrun_s[tid] = 0.f; }

    float acc[4][4];               // [jq][vc]
    float acct[4];                 // tail v=128+(vl&1), written only if vl<2
    #pragma unroll
    for (int i = 0; i < 4; ++i) {
        acct[i] = 0.f;
        #pragma unroll
        for (int v = 0; v < 4; ++v) acc[i][v] = 0.f;
    }

    const float* Kb = Kg + (size_t)b * NN * KD;
    const float* Vb = Vg + (size_t)b * NN * VD;
    const int*   Mb = maskg + b * NN;
    int n0 = c * NCHUNK;

    for (int t0 = 0; t0 < NCHUNK; t0 += TK) {
        int nbase = n0 + t0;
        __syncthreads();           // protect K_s/V_s/p_s overwrite
        for (int idx = tid; idx < TK * 32; idx += 256) {
            int r = idx >> 5, c4 = idx & 31;
            *(float4*)&K_s[r][c4 * 4] = *(const float4*)(Kb + (size_t)(nbase + r) * KD + c4 * 4);
        }
        for (int idx = tid; idx < 32 * 65; idx += 256) {
            int r = idx / 65, v2 = idx - r * 65;
            *(float2*)&V_s[r][v2 * 2] = *(const float2*)(Vb + (size_t)(nbase + r) * VD + v2 * 2);
        }
        if (tid < TK) msk_s[tid] = Mb[nbase + tid];
        __syncthreads();

        // ---- scores: 2 queries x 4 keys per thread
        float s[2][4];
        #pragma unroll
        for (int jq = 0; jq < 2; ++jq)
            #pragma unroll
            for (int t = 0; t < 4; ++t) s[jq][t] = 0.f;
        #pragma unroll 2
        for (int k = 0; k < KD; k += 4) {
            float4 q0 = *(const float4*)&q_s[qg * 2][k];
            float4 q1 = *(const float4*)&q_s[qg * 2 + 1][k];
            #pragma unroll
            for (int t = 0; t < 4; ++t) {
                float4 kv = *(const float4*)&K_s[kl + 16 * t][k];
                s[0][t] += q0.x * kv.x + q0.y * kv.y + q0.z * kv.z + q0.w * kv.w;
                s[1][t] += q1.x * kv.x + q1.y * kv.y + q1.z * kv.z + q1.w * kv.w;
            }
        }
        bool mk[4];
        #pragma unroll
        for (int t = 0; t < 4; ++t) mk[t] = msk_s[kl + 16 * t] != 0;
        const float sc = 0.08838834764831845f;
        #pragma unroll
        for (int jq = 0; jq < 2; ++jq) {
            int q = qg * 2 + jq;
            float sv[4];
            #pragma unroll
            for (int t = 0; t < 4; ++t) sv[t] = mk[t] ? -1e30f : s[jq][t] * sc;
            float tm = fmaxf(fmaxf(sv[0], sv[1]), fmaxf(sv[2], sv[3]));
            tm = fmaxf(tm, __shfl_xor(tm, 1));
            tm = fmaxf(tm, __shfl_xor(tm, 2));
            tm = fmaxf(tm, __shfl_xor(tm, 4));
            tm = fmaxf(tm, __shfl_xor(tm, 8));
            float mo = mrun_s[q];              // wave-synchronous vs kl==0 write
            float mn = fmaxf(mo, tm);
            float r = __expf(mo - mn);
            float ps = 0.f;
            #pragma unroll
            for (int t = 0; t < 4; ++t) {
                float p = mk[t] ? 0.f : __expf(sv[t] - mn);
                p_s[kl + 16 * t][q] = p;
                ps += p;
            }
            ps += __shfl_xor(ps, 1);
            ps += __shfl_xor(ps, 2);
            ps += __shfl_xor(ps, 4);
            ps += __shfl_xor(ps, 8);
            if (kl == 0) {
                mrun_s[q] = mn;
                lrun_s[q] = lrun_s[q] * r + ps;
                r_s[q] = r;
            }
        }
        __syncthreads();

        // ---- PV: rescale then accumulate sub0 (keys 0..31)
        float rr[4];
        #pragma unroll
        for (int i = 0; i < 4; ++i) rr[i] = r_s[qg4 * 4 + i];
        #pragma unroll
        for (int i = 0; i < 4; ++i) {
            acct[i] *= rr[i];
            #pragma unroll
            for (int v = 0; v < 4; ++v) acc[i][v] *= rr[i];
        }
        #pragma unroll 4
        for (int n = 0; n < 32; ++n) {
            float4 pv = *(const float4*)&p_s[n][qg4 * 4];
            float4 vv = *(const float4*)&V_s[n][vl * 4];
            float tv = V_s[n][128 + (vl & 1)];
            acc[0][0] += pv.x * vv.x; acc[0][1] += pv.x * vv.y; acc[0][2] += pv.x * vv.z; acc[0][3] += pv.x * vv.w;
            acc[1][0] += pv.y * vv.x; acc[1][1] += pv.y * vv.y; acc[1][2] += pv.y * vv.z; acc[1][3] += pv.y * vv.w;
            acc[2][0] += pv.z * vv.x; acc[2][1] += pv.z * vv.y; acc[2][2] += pv.z * vv.z; acc[2][3] += pv.z * vv.w;
            acc[3][0] += pv.w * vv.x; acc[3][1] += pv.w * vv.y; acc[3][2] += pv.w * vv.z; acc[3][3] += pv.w * vv.w;
            acct[0] += pv.x * tv; acct[1] += pv.y * tv;
            acct[2] += pv.z * tv; acct[3] += pv.w * tv;
        }
        __syncthreads();
        // load V sub1 (keys 32..63)
        for (int idx = tid; idx < 32 * 65; idx += 256) {
            int r = idx / 65, v2 = idx - r * 65;
            *(float2*)&V_s[r][v2 * 2] = *(const float2*)(Vb + (size_t)(nbase + 32 + r) * VD + v2 * 2);
        }
        __syncthreads();
        #pragma unroll 4
        for (int n = 0; n < 32; ++n) {
            float4 pv = *(const float4*)&p_s[32 + n][qg4 * 4];
            float4 vv = *(const float4*)&V_s[n][vl * 4];
            float tv = V_s[n][128 + (vl & 1)];
            acc[0][0] += pv.x * vv.x; acc[0][1] += pv.x * vv.y; acc[0][2] += pv.x * vv.z; acc[0][3] += pv.x * vv.w;
            acc[1][0] += pv.y * vv.x; acc[1][1] += pv.y * vv.y; acc[1][2] += pv.y * vv.z; acc[1][3] += pv.y * vv.w;
            acc[2][0] += pv.z * vv.x; acc[2][1] += pv.z * vv.y; acc[2][2] += pv.z * vv.z; acc[2][3] += pv.z * vv.w;
            acc[3][0] += pv.w * vv.x; acc[3][1] += pv.w * vv.y; acc[3][2] += pv.w * vv.z; acc[3][3] += pv.w * vv.w;
            acct[0] += pv.x * tv; acct[1] += pv.y * tv;
            acct[2] += pv.z * tv; acct[3] += pv.w * tv;
        }
    }
    __syncthreads();

    float* P = part + (size_t)blk * PSTRIDE;
    if (tid < JJ) { P[tid] = mrun_s[tid]; P[JJ + tid] = lrun_s[tid]; }
    float* A = P + 2 * JJ;
    #pragma unroll
    for (int i = 0; i < 4; ++i) {
        int j = qg4 * 4 + i;
        float2 lo = {acc[i][0], acc[i][1]};
        float2 hi = {acc[i][2], acc[i][3]};
        *(float2*)&A[j * VD + vl * 4] = lo;       // 8B-aligned (130j+4vl even)
        *(float2*)&A[j * VD + vl * 4 + 2] = hi;
        if (vl < 2) A[j * VD + 128 + vl] = acct[i];
    }
}

// ---------------------------------------------------------------- combine ---
__global__ __launch_bounds__(256) void comb_kernel(
        const float* __restrict__ part, float* __restrict__ attn_out) {
    int bh = blockIdx.x;           // b*H + h
    int h = bh & (HH - 1);
    int b = bh >> 2;
    int tid = threadIdx.x;
    int jg = tid >> 3;
    int l8 = tid & 7;
    __shared__ float w_s[CHUNKS][JJ];
    if (tid < JJ) {
        int j = tid;
        float m[CHUNKS], l[CHUNKS];
        float mmax = -1e30f;
        for (int cc = 0; cc < CHUNKS; ++cc) {
            const float* P = part + (size_t)(bh * CHUNKS + cc) * PSTRIDE;
            m[cc] = P[j];
            l[cc] = P[JJ + j];
            mmax = fmaxf(mmax, m[cc]);
        }
        float L = 0.f;
        float e[CHUNKS];
        for (int cc = 0; cc < CHUNKS; ++cc) {
            e[cc] = __expf(m[cc] - mmax);
            L += l[cc] * e[cc];
        }
        float inv = (L > 0.f) ? 1.0f / L : 0.f;
        for (int cc = 0; cc < CHUNKS; ++cc) w_s[cc][j] = e[cc] * inv;
    }
    __syncthreads();
    for (int v = l8; v < VD; v += 8) {
        float o = 0.f;
        for (int cc = 0; cc < CHUNKS; ++cc) {
            const float* P = part + (size_t)(bh * CHUNKS + cc) * PSTRIDE;
            o += w_s[cc][jg] * P[2 * JJ + jg * VD + v];
        }
        attn_out[(size_t)(b * JJ + jg) * (HH * VD) + h * VD + v] = o;
    }
}

// -------------------------------------------------------------- output MLP --
__global__ __launch_bounds__(64) void mlp_kernel(
        const float* __restrict__ x_in,
        const float* __restrict__ W3, const float* __restrict__ b3,
        const float* __restrict__ W4, const float* __restrict__ b4,
        const float* __restrict__ W5, const float* __restrict__ b5,
        float* __restrict__ out) {
    int row = blockIdx.x;
    int t = threadIdx.x;
    __shared__ float x[HH * VD];
    __shared__ float h1[64];
    __shared__ float h2[32];
    for (int i = t; i < HH * VD; i += 64) x[i] = x_in[(size_t)row * (HH * VD) + i];
    __syncthreads();
    float a = b3[t];
    for (int i = 0; i < HH * VD; ++i) a += x[i] * W3[i * 64 + t];
    h1[t] = fmaxf(a, 0.f);
    __syncthreads();
    if (t < 32) {
        float a2 = b4[t];
        for (int i = 0; i < 64; ++i) a2 += h1[i] * W4[i * 32 + t];
        h2[t] = fmaxf(a2, 0.f);
    }
    __syncthreads();
    if (t == 0) {
        float a3 = b5[0];
        for (int i = 0; i < 32; ++i) a3 += h2[i] * W5[i];
        out[row] = a3;
    }
}

extern "C" void kernel_launch(void* const* d_in, const int* in_sizes, int n_in,
                              void* d_out, int out_size, void* d_ws, size_t ws_size,
                              hipStream_t stream) {
    const float* jq = (const float*)d_in[0];
    const float* Kg = (const float*)d_in[1];
    const float* Vg = (const float*)d_in[2];
    const int* mask = (const int*)d_in[3];
    const float* W1 = (const float*)d_in[4];
    const float* b1 = (const float*)d_in[5];
    const float* W2 = (const float*)d_in[6];
    const float* b2 = (const float*)d_in[7];
    const float* W3 = (const float*)d_in[8];
    const float* b3 = (const float*)d_in[9];
    const float* W4 = (const float*)d_in[10];
    const float* b4 = (const float*)d_in[11];
    const float* W5 = (const float*)d_in[12];
    const float* b5 = (const float*)d_in[13];
    float* out = (float*)d_out;

    float* ws = (float*)d_ws;
    float* qenc = ws;                                        // B*J*512
    float* part = qenc + (size_t)BB * JJ * HH * KD;          // B*H*C*PSTRIDE
    float* attn = part + (size_t)BB * HH * CHUNKS * PSTRIDE; // B*J*520

    enc_kernel<<<BB * JJ, 64, 0, stream>>>(jq, W1, b1, W2, b2, qenc);
    attn_kernel<<<BB * HH * CHUNKS, 256, 0, stream>>>(Kg, Vg, mask, qenc, part);
    comb_kernel<<<BB * HH, 256, 0, stream>>>(part, attn);
    mlp_kernel<<<BB * JJ, 64, 0, stream>>>(attn, W3, b3, W4, b4, W5, b5, out);
}

// Round 3
// 202.511 us; speedup vs baseline: 22.8413x; 3.4368x over previous
//
#include <hip/hip_runtime.h>
#include <hip/hip_bf16.h>

#define BB 64
#define JJ 32
#define NN 4096
#define QD 130
#define KD 128
#define VD 130
#define HH 4
#define CHUNKS 8
#define NCHUNK (NN / CHUNKS)          // 512
#define TILES (NCHUNK / 32)           // 16
#define PSTRIDE (JJ + JJ + JJ * VD)   // 4224 floats per partial block

typedef __attribute__((ext_vector_type(8)))  __bf16 bf16x8;
typedef __attribute__((ext_vector_type(16))) float  f32x16;

union BW { __bf16 b; unsigned short s; };
union FW4 { unsigned int u[4]; bf16x8 v; };

__device__ inline unsigned short bfbits(float x) {
    BW w; w.b = (__bf16)x; return w.s;
}

// ---------------------------------------------------------------- encoder ---
__global__ __launch_bounds__(64) void enc_kernel(
        const float* __restrict__ jq,
        const float* __restrict__ W1, const float* __restrict__ b1,
        const float* __restrict__ W2, const float* __restrict__ b2,
        float* __restrict__ qenc) {
    int row = blockIdx.x;          // b*J + j
    int t = threadIdx.x;           // 0..63
    __shared__ float x[QD];
    __shared__ float h[64];
    for (int i = t; i < QD; i += 64) x[i] = jq[row * QD + i];
    __syncthreads();
    float acc = b1[t];
    for (int i = 0; i < QD; ++i) acc += x[i] * W1[i * 64 + t];
    h[t] = fmaxf(acc, 0.f);
    __syncthreads();
    for (int s = 0; s < 8; ++s) {
        int o = t + 64 * s;
        float a = b2[o];
        for (int i = 0; i < 64; ++i) a += h[i] * W2[i * 512 + o];
        qenc[row * 512 + o] = a;
    }
}

// -------------------------------------------------------------- attention ---
// Block = (b, chunk of 512 keys). 4 waves = 4 heads. Split-bf16 MFMA:
// S^T = mfma(K, Q) [32x32x16], P->A-frags in-register (T12 exchange),
// O += mfma(P, V). LDS holds fragment-linear bf16 hi/lo K and V tiles.
__global__ __launch_bounds__(256, 2) void attn_kernel(
        const float* __restrict__ Kg, const float* __restrict__ Vg,
        const int* __restrict__ maskg, const float* __restrict__ qenc,
        float* __restrict__ part) {
    int blk = blockIdx.x;
    int c = blk & (CHUNKS - 1);
    int b = blk >> 3;
    int tid = threadIdx.x;
    int wid = tid >> 6;            // head
    int lane = tid & 63;
    int l31 = lane & 31;
    int lh = lane >> 5;            // half-wave index

    // fragment-linear LDS: [plane hi/lo][kstep][lane][8 bf16]
    __shared__ __align__(16) __bf16 Kf[2][8][64][8];     // 16 KB
    __shared__ __align__(16) __bf16 Vf[2][10][64][8];    // 20 KB  (g = vt*2+ks)
    __shared__ float r_lds[4][32];

    // ---- Q B-fragments in registers (hi/lo), 8 k-steps
    bf16x8 qh[8], ql[8];
    {
        const float* qrow = qenc + (size_t)(b * JJ + l31) * 512 + wid * KD + lh * 8;
        #pragma unroll
        for (int kst = 0; kst < 8; ++kst) {
            float f[8];
            *(float4*)&f[0] = *(const float4*)(qrow + kst * 16);
            *(float4*)&f[4] = *(const float4*)(qrow + kst * 16 + 4);
            FW4 H, L;
            #pragma unroll
            for (int i = 0; i < 4; ++i) {
                __bf16 h0 = (__bf16)f[2 * i], h1 = (__bf16)f[2 * i + 1];
                BW w0, w1; w0.b = h0; w1.b = h1;
                H.u[i] = (unsigned int)w0.s | ((unsigned int)w1.s << 16);
                float r0 = f[2 * i] - (float)h0, r1 = f[2 * i + 1] - (float)h1;
                L.u[i] = (unsigned int)bfbits(r0) | ((unsigned int)bfbits(r1) << 16);
            }
            qh[kst] = H.v; ql[kst] = L.v;
        }
    }

    f32x16 O[5];
    #pragma unroll
    for (int vt = 0; vt < 5; ++vt)
        #pragma unroll
        for (int r = 0; r < 16; ++r) O[vt][r] = 0.f;
    float m_run = -1e30f, l_run = 0.f;

    const float* Kb = Kg + (size_t)b * NN * KD;
    const float* Vb = Vg + (size_t)b * NN * VD;
    const int*   Mb = maskg + b * NN;

    for (int t = 0; t < TILES; ++t) {
        int n0 = c * NCHUNK + t * 32;
        __syncthreads();
        // ---- stage K fragments (512 positions, 2 per thread)
        #pragma unroll
        for (int pp = 0; pp < 2; ++pp) {
            int p = tid + pp * 256;
            int kst = p >> 6, sl = p & 63;
            const float* src = Kb + (size_t)(n0 + (sl & 31)) * KD + kst * 16 + (sl >> 5) * 8;
            float f[8];
            *(float4*)&f[0] = *(const float4*)(src);
            *(float4*)&f[4] = *(const float4*)(src + 4);
            FW4 H, L;
            #pragma unroll
            for (int i = 0; i < 4; ++i) {
                __bf16 h0 = (__bf16)f[2 * i], h1 = (__bf16)f[2 * i + 1];
                BW w0, w1; w0.b = h0; w1.b = h1;
                H.u[i] = (unsigned int)w0.s | ((unsigned int)w1.s << 16);
                float r0 = f[2 * i] - (float)h0, r1 = f[2 * i + 1] - (float)h1;
                L.u[i] = (unsigned int)bfbits(r0) | ((unsigned int)bfbits(r1) << 16);
            }
            *(bf16x8*)&Kf[0][kst][sl][0] = H.v;
            *(bf16x8*)&Kf[1][kst][sl][0] = L.v;
        }
        // ---- stage V fragments (640 positions)
        for (int p = tid; p < 640; p += 256) {
            int g = p >> 6, sl = p & 63;
            int vt = g >> 1, ks = g & 1;
            int v = vt * 32 + (sl & 31);
            int nr = n0 + ks * 16 + (sl >> 5) * 8;
            float f[8];
            #pragma unroll
            for (int j = 0; j < 8; ++j)
                f[j] = (v < VD) ? Vb[(size_t)(nr + j) * VD + v] : 0.f;
            FW4 H, L;
            #pragma unroll
            for (int i = 0; i < 4; ++i) {
                __bf16 h0 = (__bf16)f[2 * i], h1 = (__bf16)f[2 * i + 1];
                BW w0, w1; w0.b = h0; w1.b = h1;
                H.u[i] = (unsigned int)w0.s | ((unsigned int)w1.s << 16);
                float r0 = f[2 * i] - (float)h0, r1 = f[2 * i + 1] - (float)h1;
                L.u[i] = (unsigned int)bfbits(r0) | ((unsigned int)bfbits(r1) << 16);
            }
            *(bf16x8*)&Vf[0][g][sl][0] = H.v;
            *(bf16x8*)&Vf[1][g][sl][0] = L.v;
        }
        __syncthreads();

        // ---- mask word for this 32-key tile
        int mv = Mb[n0 + l31];
        unsigned int mword = (unsigned int)__ballot(mv != 0);

        // ---- S^T = K . Q  (3-term split)
        f32x16 S;
        #pragma unroll
        for (int r = 0; r < 16; ++r) S[r] = 0.f;
        #pragma unroll
        for (int kst = 0; kst < 8; ++kst) {
            bf16x8 kh = *(const bf16x8*)&Kf[0][kst][lane][0];
            bf16x8 kl = *(const bf16x8*)&Kf[1][kst][lane][0];
            S = __builtin_amdgcn_mfma_f32_32x32x16_bf16(kh, qh[kst], S, 0, 0, 0);
            S = __builtin_amdgcn_mfma_f32_32x32x16_bf16(kh, ql[kst], S, 0, 0, 0);
            S = __builtin_amdgcn_mfma_f32_32x32x16_bf16(kl, qh[kst], S, 0, 0, 0);
        }

        // ---- mask + scale, online softmax (per-lane column q = lane&31)
        const float sc = 0.08838834764831845f;
        float sp[16];
        float rm = -1e30f;
        #pragma unroll
        for (int r = 0; r < 16; ++r) {
            int key = (r & 3) + 8 * (r >> 2) + (lh << 2);
            float s = ((mword >> key) & 1u) ? -1e30f : S[r] * sc;
            sp[r] = s;
            rm = fmaxf(rm, s);
        }
        rm = fmaxf(rm, __shfl_xor(rm, 32));
        float mn = fmaxf(m_run, rm);
        float rs = __expf(m_run - mn);
        m_run = mn;
        float ps = 0.f;
        #pragma unroll
        for (int r = 0; r < 16; ++r) {
            float p = __expf(sp[r] - mn);
            sp[r] = p;
            ps += p;
        }
        ps += __shfl_xor(ps, 32);
        l_run = l_run * rs + ps;

        if (lane < 32) r_lds[wid][lane] = rs;
        if (!__all(rs == 1.0f)) {
            float rr[16];
            #pragma unroll
            for (int r = 0; r < 16; ++r)
                rr[r] = r_lds[wid][(r & 3) + 8 * (r >> 2) + (lh << 2)];
            #pragma unroll
            for (int vt = 0; vt < 5; ++vt)
                #pragma unroll
                for (int r = 0; r < 16; ++r) O[vt][r] *= rr[r];
        }

        // ---- P -> A-fragments (hi/lo) via cross-half exchange
        bf16x8 pah[2], pal[2];
        #pragma unroll
        for (int ks = 0; ks < 2; ++ks) {
            int b0 = 8 * ks;
            unsigned int wh[4], wl[4];
            #pragma unroll
            for (int i = 0; i < 4; ++i) {
                float a = sp[b0 + 2 * i], bb = sp[b0 + 2 * i + 1];
                __bf16 ha = (__bf16)a, hb = (__bf16)bb;
                BW wa, wb; wa.b = ha; wb.b = hb;
                wh[i] = (unsigned int)wa.s | ((unsigned int)wb.s << 16);
                float la = a - (float)ha, lb = bb - (float)hb;
                wl[i] = (unsigned int)bfbits(la) | ((unsigned int)bfbits(lb) << 16);
            }
            unsigned int s0h = __shfl_xor(wh[0], 32), s1h = __shfl_xor(wh[1], 32);
            unsigned int s2h = __shfl_xor(wh[2], 32), s3h = __shfl_xor(wh[3], 32);
            unsigned int s0l = __shfl_xor(wl[0], 32), s1l = __shfl_xor(wl[1], 32);
            unsigned int s2l = __shfl_xor(wl[2], 32), s3l = __shfl_xor(wl[3], 32);
            FW4 PH, PL;
            PH.u[0] = lh ? s2h : wh[0];
            PH.u[1] = lh ? s3h : wh[1];
            PH.u[2] = lh ? wh[2] : s0h;
            PH.u[3] = lh ? wh[3] : s1h;
            PL.u[0] = lh ? s2l : wl[0];
            PL.u[1] = lh ? s3l : wl[1];
            PL.u[2] = lh ? wl[2] : s0l;
            PL.u[3] = lh ? wl[3] : s1l;
            pah[ks] = PH.v; pal[ks] = PL.v;
        }

        // ---- O += P . V (3-term split)
        #pragma unroll
        for (int ks = 0; ks < 2; ++ks) {
            #pragma unroll
            for (int vt = 0; vt < 5; ++vt) {
                bf16x8 vh = *(const bf16x8*)&Vf[0][vt * 2 + ks][lane][0];
                bf16x8 vl = *(const bf16x8*)&Vf[1][vt * 2 + ks][lane][0];
                O[vt] = __builtin_amdgcn_mfma_f32_32x32x16_bf16(pah[ks], vh, O[vt], 0, 0, 0);
                O[vt] = __builtin_amdgcn_mfma_f32_32x32x16_bf16(pal[ks], vh, O[vt], 0, 0, 0);
                O[vt] = __builtin_amdgcn_mfma_f32_32x32x16_bf16(pah[ks], vl, O[vt], 0, 0, 0);
            }
        }
    }

    // ---- write partials
    float* P = part + (size_t)((b * HH + wid) * CHUNKS + c) * PSTRIDE;
    if (lane < 32) { P[lane] = m_run; P[JJ + lane] = l_run; }
    float* A = P + 2 * JJ;
    #pragma unroll
    for (int vt = 0; vt < 5; ++vt) {
        #pragma unroll
        for (int r = 0; r < 16; ++r) {
            int q = (r & 3) + 8 * (r >> 2) + (lh << 2);
            int v = vt * 32 + l31;
            if (v < VD) A[q * VD + v] = O[vt][r];
        }
    }
}

// ---------------------------------------------------------------- combine ---
__global__ __launch_bounds__(256) void comb_kernel(
        const float* __restrict__ part, float* __restrict__ attn_out) {
    int bh = blockIdx.x;           // b*H + h
    int h = bh & (HH - 1);
    int b = bh >> 2;
    int tid = threadIdx.x;
    int jg = tid >> 3;
    int l8 = tid & 7;
    __shared__ float w_s[CHUNKS][JJ];
    if (tid < JJ) {
        int j = tid;
        float m[CHUNKS], l[CHUNKS];
        float mmax = -1e30f;
        for (int cc = 0; cc < CHUNKS; ++cc) {
            const float* P = part + (size_t)(bh * CHUNKS + cc) * PSTRIDE;
            m[cc] = P[j];
            l[cc] = P[JJ + j];
            mmax = fmaxf(mmax, m[cc]);
        }
        float L = 0.f;
        float e[CHUNKS];
        for (int cc = 0; cc < CHUNKS; ++cc) {
            e[cc] = __expf(m[cc] - mmax);
            L += l[cc] * e[cc];
        }
        float inv = (L > 0.f) ? 1.0f / L : 0.f;
        for (int cc = 0; cc < CHUNKS; ++cc) w_s[cc][j] = e[cc] * inv;
    }
    __syncthreads();
    for (int v = l8; v < VD; v += 8) {
        float o = 0.f;
        for (int cc = 0; cc < CHUNKS; ++cc) {
            const float* P = part + (size_t)(bh * CHUNKS + cc) * PSTRIDE;
            o += w_s[cc][jg] * P[2 * JJ + jg * VD + v];
        }
        attn_out[(size_t)(b * JJ + jg) * (HH * VD) + h * VD + v] = o;
    }
}

// -------------------------------------------------------------- output MLP --
__global__ __launch_bounds__(64) void mlp_kernel(
        const float* __restrict__ x_in,
        const float* __restrict__ W3, const float* __restrict__ b3,
        const float* __restrict__ W4, const float* __restrict__ b4,
        const float* __restrict__ W5, const float* __restrict__ b5,
        float* __restrict__ out) {
    int row = blockIdx.x;
    int t = threadIdx.x;
    __shared__ float x[HH * VD];
    __shared__ float h1[64];
    __shared__ float h2[32];
    for (int i = t; i < HH * VD; i += 64) x[i] = x_in[(size_t)row * (HH * VD) + i];
    __syncthreads();
    float a = b3[t];
    for (int i = 0; i < HH * VD; ++i) a += x[i] * W3[i * 64 + t];
    h1[t] = fmaxf(a, 0.f);
    __syncthreads();
    if (t < 32) {
        float a2 = b4[t];
        for (int i = 0; i < 64; ++i) a2 += h1[i] * W4[i * 32 + t];
        h2[t] = fmaxf(a2, 0.f);
    }
    __syncthreads();
    if (t == 0) {
        float a3 = b5[0];
        for (int i = 0; i < 32; ++i) a3 += h2[i] * W5[i];
        out[row] = a3;
    }
}

extern "C" void kernel_launch(void* const* d_in, const int* in_sizes, int n_in,
                              void* d_out, int out_size, void* d_ws, size_t ws_size,
                              hipStream_t stream) {
    const float* jq = (const float*)d_in[0];
    const float* Kg = (const float*)d_in[1];
    const float* Vg = (const float*)d_in[2];
    const int* mask = (const int*)d_in[3];
    const float* W1 = (const float*)d_in[4];
    const float* b1 = (const float*)d_in[5];
    const float* W2 = (const float*)d_in[6];
    const float* b2 = (const float*)d_in[7];
    const float* W3 = (const float*)d_in[8];
    const float* b3 = (const float*)d_in[9];
    const float* W4 = (const float*)d_in[10];
    const float* b4 = (const float*)d_in[11];
    const float* W5 = (const float*)d_in[12];
    const float* b5 = (const float*)d_in[13];
    float* out = (float*)d_out;

    float* ws = (float*)d_ws;
    float* qenc = ws;                                        // B*J*512      = 1,048,576 f
    float* part = qenc + (size_t)BB * JJ * HH * KD;          // B*H*8*PSTRIDE= 8,650,752 f
    float* attn = part + (size_t)BB * HH * CHUNKS * PSTRIDE; // B*J*520      = 1,064,960 f

    enc_kernel<<<BB * JJ, 64, 0, stream>>>(jq, W1, b1, W2, b2, qenc);
    attn_kernel<<<BB * CHUNKS, 256, 0, stream>>>(Kg, Vg, mask, qenc, part);
    comb_kernel<<<BB * HH, 256, 0, stream>>>(part, attn);
    mlp_kernel<<<BB * JJ, 64, 0, stream>>>(attn, W3, b3, W4, b4, W5, b5, out);
}